// Round 14
// baseline (90.870 us; speedup 1.0000x reference)
//
#include <hip/hip_runtime.h>

#define HH 128
#define WW 128
#define SBUF 36864             // sbuf base (wbuf occupies [0, 36864))

typedef __bf16 bf16x8 __attribute__((ext_vector_type(8)));
typedef __bf16 bf16x2 __attribute__((ext_vector_type(2)));
typedef float f32x4 __attribute__((ext_vector_type(4)));

static __device__ __forceinline__ unsigned short f2bf(float f) {
  unsigned int u = __float_as_uint(f);
  u = (u + 0x7FFFu + ((u >> 16) & 1u)) >> 16;  // RNE
  return (unsigned short)u;
}

static __device__ __forceinline__ unsigned int pack2bf(float lo, float hi) {
  bf16x2 v;
  v[0] = (__bf16)lo;
  v[1] = (__bf16)hi;
  return __builtin_bit_cast(unsigned int, v);
}

// ---------------------------------------------------------------------------
// Merged prep: blocks [0,144) pack conv_w into MFMA A-fragment order;
// blocks [144,152) build the 9-case boundary table for the extra conv.
//   wfrag[f = h*9+tap][cotile][lane][i] = conv_w[cot*16+lane%16][h*32+(lane/16)*8+i][tap]
//   ext[b][co][cy][cx] includes conv_b + extra_b.
// ---------------------------------------------------------------------------
__global__ __launch_bounds__(256) void prep_all(const float* __restrict__ conv_w,
                                                const float* __restrict__ extra_in,
                                                const float* __restrict__ extra_w,
                                                const float* __restrict__ conv_b,
                                                const float* __restrict__ extra_b,
                                                unsigned short* __restrict__ wfrag,
                                                float* __restrict__ ext) {
  if (blockIdx.x < 144) {
    int tid = blockIdx.x * 256 + threadIdx.x;
    if (tid >= 18 * 2048) return;
    int i    = tid & 7;
    int lane = (tid >> 3) & 63;
    int cot  = (tid >> 9) & 3;
    int f    = tid >> 11;           // 0..17
    int h    = f / 9;
    int tap  = f - h * 9;
    int co   = cot * 16 + (lane & 15);
    int ci   = h * 32 + (lane >> 4) * 8 + i;
    wfrag[tid] = f2bf(conv_w[(co * 64 + ci) * 9 + tap]);
    return;
  }
  int t = (blockIdx.x - 144) * 256 + threadIdx.x;
  if (t >= 32 * 64) return;
  int b = t >> 6, co = t & 63;
  float base = conv_b[co] + extra_b[co];
  float acc[3][3];
#pragma unroll
  for (int i = 0; i < 3; ++i)
#pragma unroll
    for (int j = 0; j < 3; ++j) acc[i][j] = 0.f;
#pragma unroll
  for (int f = 0; f < 3; ++f) {
    float e = extra_in[b * 192 + co * 3 + f];
    const float* w = extra_w + (co * 3 + f) * 9;
    float rs[3][3];
#pragma unroll
    for (int ky = 0; ky < 3; ++ky) {
      float w0 = w[ky * 3 + 0], w1 = w[ky * 3 + 1], w2 = w[ky * 3 + 2];
      rs[ky][0] = w1 + w2;
      rs[ky][1] = w0 + w1 + w2;
      rs[ky][2] = w0 + w1;
    }
#pragma unroll
    for (int cx = 0; cx < 3; ++cx) {
      acc[0][cx] += e * (rs[1][cx] + rs[2][cx]);
      acc[1][cx] += e * (rs[0][cx] + rs[1][cx] + rs[2][cx]);
      acc[2][cx] += e * (rs[0][cx] + rs[1][cx]);
    }
  }
#pragma unroll
  for (int cy = 0; cy < 3; ++cy)
#pragma unroll
    for (int cx = 0; cx < 3; ++cx)
      ext[t * 9 + cy * 3 + cx] = base + acc[cy][cx];
}

// ---------------------------------------------------------------------------
// Main: co-split implicit-GEMM conv (mfma_f32_16x16x32_bf16).
// Block = (batch, co-half of 32, 4-row tile, x-half of 64): 256 thr = 4
// waves, wave = output row. 4096 blocks, LDS 63 KB -> 2 blocks/CU; overlap
// comes from the co-resident sibling block (desynced phases), not intra-
// block pipelining. Staging is duplicated across the 2 co-halves of a tile
// (reads are L2/L3-hot; FETCH rises only modestly).
//  - wbuf 36 KB: this co-half's slice of wfrag, DMA'd once per block.
//  - sbuf 25.5 KB: [6r][68c][32ci] bf16, ci-halves staged serially.
//  - float4 quad staging + cvt_pk pack; XCD chunk swizzle (4096 % 8 == 0);
//    plain cached stores (r11 epilogue — WRITE stays 131 MB).
// ---------------------------------------------------------------------------
__global__ __launch_bounds__(256, 2) void conv_half(const float* __restrict__ x,
                                                    const unsigned short* __restrict__ wfrag,
                                                    const float* __restrict__ ext,
                                                    float* __restrict__ out) {
  // XCD chunk swizzle: each XCD gets 512 consecutive works = 4 full batches
  const int orig = blockIdx.x;
  const int w    = (orig & 7) * 512 + (orig >> 3);
  const int b    = w >> 7;          // 32 batches
  const int ch   = (w >> 6) & 1;    // co half
  const int yt   = (w >> 1) & 31;   // 4-row tile
  const int xh   = w & 1;

  const int ybase = yt * 4;
  const int x0    = xh * 64;
  const int tid  = threadIdx.x;
  const int lane = tid & 63;
  const int wv   = tid >> 6;        // wave id = output row
  const int pix  = lane & 15;
  const int g    = lane >> 4;

  __shared__ __align__(16) unsigned char lds[SBUF + 26112];  // 62976 B

  const float* xb   = x + (size_t)b * 64 * HH * WW;
  const float* extb = ext + (size_t)b * 64 * 9;

  // ---- weights: DMA this co-half's 36 KB slice once ----
  // dst byte d -> f = d>>11, rem = d&2047; src byte = f*4096 + ch*2048 + rem
#pragma unroll
  for (int it = 0; it < 9; ++it) {
    int d = (tid + it * 256) * 16;
    int srcb = ((d >> 11) << 12) + (ch << 11) + (d & 2047);
    __builtin_amdgcn_global_load_lds(
        (const __attribute__((address_space(1))) unsigned int*)((const char*)wfrag + srcb),
        (__attribute__((address_space(3))) unsigned int*)(lds + d), 16, 0, 0);
  }

  // ---- stage one ci-half (h) of the 6x66 halo into sbuf ----
  auto stage_half = [&](int h) {
    unsigned char* sb = lds + SBUF;
    // interior: quad items (4 px x 8 ci): 16 qd x 4 cig x 6 r = 384
#pragma unroll
    for (int it = 0; it < 2; ++it) {
      int q = tid + it * 256;
      if (q < 384) {
        int qd  = q & 15;
        int cig = (q >> 4) & 3;
        int r   = q >> 6;            // 0..5
        int gy  = ybase - 1 + r;
        int cc  = 1 + 4 * qd;
        int x_in = x0 + 4 * qd;      // 16B-aligned float4
        float4 f[8];
        if ((unsigned)gy < 128u) {
          const float* src = xb + (size_t)(h * 32 + cig * 8) * (HH * WW) + gy * WW + x_in;
#pragma unroll
          for (int j = 0; j < 8; ++j) f[j] = *(const float4*)(src + (size_t)j * (HH * WW));
        } else {
#pragma unroll
          for (int j = 0; j < 8; ++j) f[j] = make_float4(0.f, 0.f, 0.f, 0.f);
        }
#pragma unroll
        for (int p = 0; p < 4; ++p) {
          const int cp = cc + p;
          unsigned int pk[4];
#pragma unroll
          for (int ww = 0; ww < 4; ++ww) {
            const float* lo = (const float*)&f[2 * ww];
            const float* hi = (const float*)&f[2 * ww + 1];
            pk[ww] = pack2bf(lo[p], hi[p]);
          }
          int byte = ((r * 68 + cp) * 64 + cig * 16) ^ (((cp ^ (cp >> 2)) & 3) << 4);
          *(uint4*)(sb + byte) = make_uint4(pk[0], pk[1], pk[2], pk[3]);
        }
      }
    }
    // border cols {0, 65}: 48 items
    if (tid < 48) {
      int cc  = (tid & 1) ? 65 : 0;
      int cig = (tid >> 1) & 3;
      int r   = tid >> 3;            // 0..5
      int gy  = ybase - 1 + r;
      int x_in = x0 - 1 + cc;
      bool inb = ((unsigned)gy < 128u) & ((unsigned)x_in < 128u);
      unsigned int pk[4] = {0u, 0u, 0u, 0u};
      if (inb) {
        const float* src = xb + (size_t)(h * 32 + cig * 8) * (HH * WW) + gy * WW + x_in;
        float v[8];
#pragma unroll
        for (int j = 0; j < 8; ++j) v[j] = src[(size_t)j * (HH * WW)];
#pragma unroll
        for (int ww = 0; ww < 4; ++ww) pk[ww] = pack2bf(v[2 * ww], v[2 * ww + 1]);
      }
      int byte = ((r * 68 + cc) * 64 + cig * 16) ^ (((cc ^ (cc >> 2)) & 3) << 4);
      *(uint4*)(sb + byte) = make_uint4(pk[0], pk[1], pk[2], pk[3]);
    }
  };

  f32x4 acc[2][4];
#pragma unroll
  for (int i = 0; i < 2; ++i)
#pragma unroll
    for (int j = 0; j < 4; ++j) acc[i][j] = (f32x4){0.f, 0.f, 0.f, 0.f};

  auto compute_half = [&](int h) {
    const unsigned char* sb = lds + SBUF;
#pragma unroll
    for (int tap = 0; tap < 9; ++tap) {
      const int ky = tap / 3, kx = tap - ky * 3;
      bf16x8 af[2];
#pragma unroll
      for (int cotl = 0; cotl < 2; ++cotl)
        af[cotl] = *(const bf16x8*)(lds + (h * 9 + tap) * 2048 + cotl * 1024 + lane * 16);
      bf16x8 pf[4];
      const int r = wv + ky;
#pragma unroll
      for (int m = 0; m < 4; ++m) {
        int cc = m * 16 + pix + kx;
        int byte = ((r * 68 + cc) * 64 + g * 16) ^ (((cc ^ (cc >> 2)) & 3) << 4);
        pf[m] = *(const bf16x8*)(sb + byte);
      }
#pragma unroll
      for (int cotl = 0; cotl < 2; ++cotl)
#pragma unroll
        for (int m = 0; m < 4; ++m)
          acc[cotl][m] = __builtin_amdgcn_mfma_f32_16x16x32_bf16(af[cotl], pf[m],
                                                                 acc[cotl][m], 0, 0, 0);
    }
  };

  stage_half(0);
  __syncthreads();   // drains weights DMA too
  compute_half(0);
  __syncthreads();
  stage_half(1);
  __syncthreads();
  compute_half(1);

  // ---- epilogue: add boundary-case table, direct cached stores ----
  const int y  = ybase + wv;
  const int cy = (y == 0) ? 0 : ((y == HH - 1) ? 2 : 1);
#pragma unroll
  for (int cotl = 0; cotl < 2; ++cotl) {
#pragma unroll
    for (int m = 0; m < 4; ++m) {
      int xg = x0 + m * 16 + pix;
      int cx = (xg == 0) ? 0 : ((xg == WW - 1) ? 2 : 1);
#pragma unroll
      for (int j = 0; j < 4; ++j) {
        int co = ch * 32 + cotl * 16 + g * 4 + j;
        out[(((size_t)b * 64 + co) * HH + y) * WW + xg] =
            acc[cotl][m][j] + extb[co * 9 + cy * 3 + cx];
      }
    }
  }
}

extern "C" void kernel_launch(void* const* d_in, const int* in_sizes, int n_in,
                              void* d_out, int out_size, void* d_ws, size_t ws_size,
                              hipStream_t stream) {
  const float* x        = (const float*)d_in[0];
  const float* extra_in = (const float*)d_in[1];
  const float* conv_w   = (const float*)d_in[2];
  const float* conv_b   = (const float*)d_in[3];
  const float* extra_w  = (const float*)d_in[4];
  const float* extra_b  = (const float*)d_in[5];
  float* out = (float*)d_out;

  unsigned short* wfrag = (unsigned short*)d_ws;              // 73728 B
  float* ext = (float*)((char*)d_ws + 73728);                 // 73728 B

  hipLaunchKernelGGL(prep_all, dim3(152), dim3(256), 0, stream,
                     conv_w, extra_in, extra_w, conv_b, extra_b, wfrag, ext);
  hipLaunchKernelGGL(conv_half, dim3(4096), dim3(256), 0, stream,
                     x, wfrag, ext, out);
}